// Round 1
// baseline (379.765 us; speedup 1.0000x reference)
//
#include <hip/hip_runtime.h>

// BiLSTM (diagonal, PixelRNN-style) on MI355X.
// Layouts: pixel-major [p][c] with p = (b*32+h)*32+w. hmap bf16 [16384][256].
// lh double-buffered bf16 [16384][64] per stream; lc fp32 per-pixel private.
// Weights pre-transposed to [n][k] bf16 so MFMA B-fragments are 16B row loads.

using bf16   = __bf16;
using bf16x8 = __attribute__((ext_vector_type(8))) __bf16;
using f32x4  = __attribute__((ext_vector_type(4))) float;

#define NB   16
#define HH   32
#define WW   32
#define NPIX (NB * HH * WW)  // 16384

__device__ __forceinline__ float sigf(float x) {
  // 1/(1+exp(-x)); exp overflow -> inf -> rcp -> 0 (safe at both tails)
  return __builtin_amdgcn_rcpf(1.0f + __expf(-x));
}
__device__ __forceinline__ float tanh_fast(float x) {
  return 2.0f * __builtin_amdgcn_rcpf(1.0f + __expf(-2.0f * x)) - 1.0f;
}
__device__ __forceinline__ bf16x8 bzero8() {
  bf16x8 v;
#pragma unroll
  for (int e = 0; e < 8; ++e) v[e] = (bf16)0.0f;
  return v;
}

// ---------------- prep: weights -> bf16, [n][k] layouts ----------------
__global__ void prep_kernel(const float* __restrict__ w_i2s,
                            const float* __restrict__ w_left,
                            const float* __restrict__ w_right,
                            const float* __restrict__ w_skip,
                            bf16* __restrict__ WnI, bf16* __restrict__ WnL,
                            bf16* __restrict__ WnR, bf16* __restrict__ WnS) {
  int t = blockIdx.x * 256 + threadIdx.x;
  if (t < 32768) {
    WnI[t] = (bf16)w_i2s[t];  // [256][128] o-major == desired [n][k]
    int o = t >> 7, k = t & 127;
    // k<64: tap0 (h-1, w+-1) -> w[:,:,0]; k>=64: tap1 (h, w+-1) -> w[:,:,1]
    int src = (k < 64) ? (o * 128 + k * 2) : (o * 128 + (k - 64) * 2 + 1);
    WnL[t] = (bf16)w_left[src];
    WnR[t] = (bf16)w_right[src];
    if (t < 8192) WnS[t] = (bf16)w_skip[t];  // [128][64]
  }
}

// ---------------- hmap = x @ w_i2s^T : M=16384,K=128,N=256 ----------------
__global__ __launch_bounds__(256, 2)
void hmap_kernel(const float* __restrict__ x, const bf16* __restrict__ Wn,
                 bf16* __restrict__ hmap) {
  __shared__ __align__(16) bf16 At[64 * 128];  // XOR-swizzled
  const int tile = blockIdx.x;  // 256 tiles: 64 px each (2 rows of one batch)
  const int b = tile >> 4, h0 = (tile & 15) << 1;
  const int t = threadIdx.x;
  const float* xb = x + (size_t)(b * 128) * 1024 + h0 * 32;
  // stage A: x is planar [c][pix]; 64 px contiguous per channel row
#pragma unroll
  for (int i = 0; i < 8; ++i) {
    int idx = t + 256 * i;          // [0,2048)
    int c = idx >> 4, m4 = idx & 15;
    f32x4 v = *(const f32x4*)(xb + (size_t)c * 1024 + m4 * 4);
#pragma unroll
    for (int e = 0; e < 4; ++e) {
      int m = m4 * 4 + e;
      int kb = (c * 2) ^ ((m & 7) << 4);
      *(bf16*)((char*)At + m * 256 + kb) = (bf16)v[e];
    }
  }
  __syncthreads();
  const int wv = t >> 6, l = t & 63;
  const int l15 = l & 15, lq = l >> 4;
  bf16x8 bfrag[4][4];
#pragma unroll
  for (int q = 0; q < 4; ++q)
#pragma unroll
    for (int kk = 0; kk < 4; ++kk)
      bfrag[q][kk] =
          *(const bf16x8*)(Wn + (q * 64 + wv * 16 + l15) * 128 + kk * 32 + lq * 8);
  f32x4 acc[4][4];
  const f32x4 fz = {0.f, 0.f, 0.f, 0.f};
#pragma unroll
  for (int ms = 0; ms < 4; ++ms)
#pragma unroll
    for (int q = 0; q < 4; ++q) acc[ms][q] = fz;
#pragma unroll
  for (int kk = 0; kk < 4; ++kk) {
#pragma unroll
    for (int ms = 0; ms < 4; ++ms) {
      int m = ms * 16 + l15;
      int kb = ((kk * 32 + lq * 8) * 2) ^ ((m & 7) << 4);
      bf16x8 a = *(const bf16x8*)((const char*)At + m * 256 + kb);
#pragma unroll
      for (int q = 0; q < 4; ++q)
        acc[ms][q] =
            __builtin_amdgcn_mfma_f32_16x16x32_bf16(a, bfrag[q][kk], acc[ms][q], 0, 0, 0);
    }
  }
  const int pix0 = tile * 64;
#pragma unroll
  for (int ms = 0; ms < 4; ++ms)
#pragma unroll
    for (int q = 0; q < 4; ++q)
#pragma unroll
      for (int j = 0; j < 4; ++j) {
        int p = pix0 + ms * 16 + lq * 4 + j;
        int n = q * 64 + wv * 16 + l15;
        hmap[(size_t)p * 256 + n] = (bf16)acc[ms][q][j];
      }
}

// ---------------- one scan step, both streams ----------------
// blocks [0,256): left stream; [256,512): right stream. Tile = 64 px.
__global__ __launch_bounds__(256, 2)
void step_kernel(const bf16* __restrict__ lhL_in, bf16* __restrict__ lhL_out,
                 const bf16* __restrict__ lhR_in, bf16* __restrict__ lhR_out,
                 float* __restrict__ lcL, float* __restrict__ lcR,
                 const bf16* __restrict__ hmap,
                 const bf16* __restrict__ WnL, const bf16* __restrict__ WnR,
                 const float* __restrict__ bL, const float* __restrict__ bR) {
  __shared__ __align__(16) bf16 At[64 * 128];
  const int blk = blockIdx.x;
  const bool right = blk >= 256;
  const int tile = right ? blk - 256 : blk;
  const bf16* __restrict__ lh_in = right ? lhR_in : lhL_in;
  bf16* __restrict__ lh_out = right ? lhR_out : lhL_out;
  float* __restrict__ lc = right ? lcR : lcL;
  const bf16* __restrict__ Wn = right ? WnR : WnL;
  const float* __restrict__ bias = right ? bR : bL;
  const int b = tile >> 4, h0 = (tile & 15) << 1;
  const int t = threadIdx.x;
  const int dw = right ? 1 : -1;
  // stage A: [m][k] k<64 = lh(h-1, w+dw), k>=64 = lh(h, w+dw); OOB -> 0
#pragma unroll
  for (int i = 0; i < 4; ++i) {
    int idx = t + 256 * i;  // [0,1024)
    int tap = idx >> 9, rem = idx & 511, m = rem >> 3, c8 = rem & 7;
    int h = h0 + (m >> 5), w = m & 31;
    int wsrc = w + dw;
    int hsrc = (tap == 0) ? h - 1 : h;
    bf16x8 v;
    if (wsrc < 0 || wsrc > 31 || hsrc < 0)
      v = bzero8();
    else
      v = *(const bf16x8*)(lh_in + (size_t)((b * 32 + hsrc) * 32 + wsrc) * 64 + c8 * 8);
    int kb = (tap * 128 + c8 * 16) ^ ((m & 7) << 4);
    *(bf16x8*)((char*)At + m * 256 + kb) = v;
  }
  __syncthreads();
  const int wv = t >> 6, l = t & 63;
  const int l15 = l & 15, lq = l >> 4;
  const int c = wv * 16 + l15;  // channel this lane owns (gate-interleaved N)
  float bq[4];
#pragma unroll
  for (int q = 0; q < 4; ++q) bq[q] = bias[q * 64 + c];
  bf16x8 bfrag[4][4];
#pragma unroll
  for (int q = 0; q < 4; ++q)
#pragma unroll
    for (int kk = 0; kk < 4; ++kk)
      bfrag[q][kk] = *(const bf16x8*)(Wn + (q * 64 + c) * 128 + kk * 32 + lq * 8);
  f32x4 acc[4][4];
  const f32x4 fz = {0.f, 0.f, 0.f, 0.f};
#pragma unroll
  for (int ms = 0; ms < 4; ++ms)
#pragma unroll
    for (int q = 0; q < 4; ++q) acc[ms][q] = fz;
#pragma unroll
  for (int kk = 0; kk < 4; ++kk) {
#pragma unroll
    for (int ms = 0; ms < 4; ++ms) {
      int m = ms * 16 + l15;
      int kb = ((kk * 32 + lq * 8) * 2) ^ ((m & 7) << 4);
      bf16x8 a = *(const bf16x8*)((const char*)At + m * 256 + kb);
#pragma unroll
      for (int q = 0; q < 4; ++q)
        acc[ms][q] =
            __builtin_amdgcn_mfma_f32_16x16x32_bf16(a, bfrag[q][kk], acc[ms][q], 0, 0, 0);
    }
  }
  // epilogue: all 4 gates of (p, c) live in this lane
  const int pix0 = tile * 64;
#pragma unroll
  for (int ms = 0; ms < 4; ++ms) {
#pragma unroll
    for (int j = 0; j < 4; ++j) {
      int p = pix0 + ms * 16 + lq * 4 + j;
      float pre[4];
#pragma unroll
      for (int q = 0; q < 4; ++q)
        pre[q] = acc[ms][q][j] + (float)hmap[(size_t)p * 256 + q * 64 + c] + bq[q];
      float og = sigf(pre[0]);
      float fg = sigf(pre[1]);
      float ig = sigf(pre[2]);
      float gg = sigf(pre[3]);
      float lcv = fg * lc[(size_t)p * 64 + c] + ig * gg;
      lc[(size_t)p * 64 + c] = lcv;
      lh_out[(size_t)p * 64 + c] = (bf16)(og * tanh_fast(lcv));
    }
  }
}

// ---------------- final: out = x + (lhL + shift_down(lhR)) @ w_skip^T + b ----------------
__global__ __launch_bounds__(256, 2)
void final_kernel(const float* __restrict__ x, const bf16* __restrict__ lhL,
                  const bf16* __restrict__ lhR, const bf16* __restrict__ Wn,
                  const float* __restrict__ b_skip, float* __restrict__ out) {
  __shared__ __align__(16) bf16 At[64 * 64];
  __shared__ __align__(16) float smemT[128 * 72];  // [o2][m], padded rows
  const int tile = blockIdx.x;
  const int b = tile >> 4, h0 = (tile & 15) << 1;
  const int t = threadIdx.x;
#pragma unroll
  for (int i = 0; i < 2; ++i) {
    int idx = t + 256 * i;  // [0,512)
    int m = idx >> 3, c8 = idx & 7;
    int h = h0 + (m >> 5), w = m & 31;
    size_t p = (size_t)(b * 32 + h) * 32 + w;
    bf16x8 vL = *(const bf16x8*)(lhL + p * 64 + c8 * 8);
    bf16x8 v;
    if (h > 0) {
      bf16x8 vR = *(const bf16x8*)(lhR + (p - 32) * 64 + c8 * 8);
#pragma unroll
      for (int e = 0; e < 8; ++e) v[e] = (bf16)((float)vL[e] + (float)vR[e]);
    } else {
      v = vL;
    }
    int kb = (c8 * 16) ^ ((m & 7) << 4);
    *(bf16x8*)((char*)At + m * 128 + kb) = v;
  }
  __syncthreads();
  const int wv = t >> 6, l = t & 63;
  const int l15 = l & 15, lq = l >> 4;
  const int c = wv * 16 + l15;
  bf16x8 bfrag[2][2];
#pragma unroll
  for (int q = 0; q < 2; ++q)
#pragma unroll
    for (int kk = 0; kk < 2; ++kk)
      bfrag[q][kk] = *(const bf16x8*)(Wn + (q * 64 + c) * 64 + kk * 32 + lq * 8);
  f32x4 acc[4][2];
  const f32x4 fz = {0.f, 0.f, 0.f, 0.f};
#pragma unroll
  for (int ms = 0; ms < 4; ++ms)
#pragma unroll
    for (int q = 0; q < 2; ++q) acc[ms][q] = fz;
#pragma unroll
  for (int kk = 0; kk < 2; ++kk) {
#pragma unroll
    for (int ms = 0; ms < 4; ++ms) {
      int m = ms * 16 + l15;
      int kb = ((kk * 32 + lq * 8) * 2) ^ ((m & 7) << 4);
      bf16x8 a = *(const bf16x8*)((const char*)At + m * 128 + kb);
#pragma unroll
      for (int q = 0; q < 2; ++q)
        acc[ms][q] =
            __builtin_amdgcn_mfma_f32_16x16x32_bf16(a, bfrag[q][kk], acc[ms][q], 0, 0, 0);
    }
  }
  float bsk[2];
#pragma unroll
  for (int q = 0; q < 2; ++q) bsk[q] = b_skip[q * 64 + c];
#pragma unroll
  for (int ms = 0; ms < 4; ++ms)
#pragma unroll
    for (int q = 0; q < 2; ++q)
#pragma unroll
      for (int j = 0; j < 4; ++j) {
        int m = ms * 16 + lq * 4 + j;
        int n = q * 64 + c;
        smemT[n * 72 + m] = acc[ms][q][j] + bsk[q];
      }
  __syncthreads();
  const float* xb = x + (size_t)(b * 128) * 1024 + h0 * 32;
  float* ob = out + (size_t)(b * 128) * 1024 + h0 * 32;
#pragma unroll
  for (int i = 0; i < 8; ++i) {
    int idx = t + 256 * i;  // [0,2048)
    int o2 = idx >> 4, m4 = idx & 15;
    f32x4 s = *(const f32x4*)(&smemT[o2 * 72 + m4 * 4]);
    f32x4 xv = *(const f32x4*)(xb + (size_t)o2 * 1024 + m4 * 4);
#pragma unroll
    for (int e = 0; e < 4; ++e) s[e] += xv[e];
    *(f32x4*)(ob + (size_t)o2 * 1024 + m4 * 4) = s;
  }
}

extern "C" void kernel_launch(void* const* d_in, const int* in_sizes, int n_in,
                              void* d_out, int out_size, void* d_ws, size_t ws_size,
                              hipStream_t stream) {
  const float* x       = (const float*)d_in[0];
  const float* w_i2s   = (const float*)d_in[1];
  const float* w_left  = (const float*)d_in[2];
  const float* b_left  = (const float*)d_in[3];
  const float* w_right = (const float*)d_in[4];
  const float* b_right = (const float*)d_in[5];
  const float* w_skip  = (const float*)d_in[6];
  const float* b_skip  = (const float*)d_in[7];
  float* out = (float*)d_out;
  char* ws = (char*)d_ws;

  // ws layout (bytes); total ~24.2 MB
  bf16*  lhL[2] = {(bf16*)(ws + 0),        (bf16*)(ws + 12582912)};
  bf16*  lhR[2] = {(bf16*)(ws + 2097152),  (bf16*)(ws + 14680064)};
  float* lcL    = (float*)(ws + 4194304);
  float* lcR    = (float*)(ws + 8388608);
  bf16*  hmap   = (bf16*)(ws + 16777216);
  bf16*  WnL    = (bf16*)(ws + 25165824);
  bf16*  WnR    = (bf16*)(ws + 25231360);
  bf16*  WnI    = (bf16*)(ws + 25296896);
  bf16*  WnS    = (bf16*)(ws + 25362432);

  // zero initial state: lhL[0], lhR[0], lcL, lcR (contiguous first 12 MB)
  hipMemsetAsync(ws, 0, 12582912, stream);
  prep_kernel<<<128, 256, 0, stream>>>(w_i2s, w_left, w_right, w_skip, WnI, WnL, WnR, WnS);
  hmap_kernel<<<256, 256, 0, stream>>>(x, WnI, hmap);
  for (int s = 0; s < 32; ++s) {
    step_kernel<<<512, 256, 0, stream>>>(lhL[s & 1], lhL[(s + 1) & 1],
                                         lhR[s & 1], lhR[(s + 1) & 1],
                                         lcL, lcR, hmap, WnL, WnR, b_left, b_right);
  }
  // after 32 steps, final state is back in buffer 0
  final_kernel<<<256, 256, 0, stream>>>(x, lhL[0], lhR[0], WnS, b_skip, out);
}